// Round 4
// baseline (263.507 us; speedup 1.0000x reference)
//
#include <hip/hip_runtime.h>

// Problem constants: B=8, T=2048, C=1024, H=128
constexpr int kB = 8;
constexpr int kT = 2048;
constexpr int kC = 1024;
constexpr int kH = 128;
constexpr int kM = kB * kT;                 // 16384 rows
constexpr size_t kMH = (size_t)kM * kH;     // 2,097,152
constexpr size_t kWH = (size_t)kC * kH;     // 131,072

// q is pre-scaled by sqrt(C)*log2(e) so softmax can use exp2 directly.
#define QSCALE 46.166241308446828f          // 32 * 1.4426950408889634

typedef __attribute__((ext_vector_type(8))) short bf16x8;   // MFMA A/B frag
typedef __attribute__((ext_vector_type(4))) float f32x4;    // MFMA C/D frag

// ws layout (ushort): qhi | qlo | khi | klo | vT[B][H][T] | 6x WT (hi/lo per mat)

__device__ inline unsigned short f2bf_rne(float f) {
    union { float f; unsigned int u; } x; x.f = f;
    unsigned int r = x.u + 0x7fff + ((x.u >> 16) & 1);
    return (unsigned short)(r >> 16);
}
__device__ inline float bf2f(unsigned short h) {
    union { float f; unsigned int u; } x; x.u = ((unsigned int)h) << 16;
    return x.f;
}
__device__ inline unsigned int pack_hi2(float a, float b) {  // trunc-hi16 pack
    return __builtin_amdgcn_perm(__float_as_uint(b), __float_as_uint(a),
                                 0x07060302u);
}
__device__ inline float hi_part(float v) {
    return __uint_as_float(__float_as_uint(v) & 0xffff0000u);
}
__device__ inline void load_lds16(const unsigned short* g, unsigned short* l) {
    __builtin_amdgcn_global_load_lds(
        (const __attribute__((address_space(1))) unsigned int*)g,
        (__attribute__((address_space(3))) unsigned int*)l, 16, 0, 0);
}

// ---- DPP 16-lane row reductions (pure VALU: no ds_bpermute, no lgkmcnt) ----
template <int CTRL>
__device__ inline float dpp_rot(float x) {
    return __int_as_float(__builtin_amdgcn_update_dpp(
        0, __float_as_int(x), CTRL, 0xf, 0xf, false));
}
__device__ inline float rowmax16(float x) {
    x = fmaxf(x, dpp_rot<0x121>(x));   // ror:1
    x = fmaxf(x, dpp_rot<0x122>(x));   // ror:2
    x = fmaxf(x, dpp_rot<0x124>(x));   // ror:4
    x = fmaxf(x, dpp_rot<0x128>(x));   // ror:8
    return x;
}
__device__ inline float rowsum16(float x) {
    x += dpp_rot<0x121>(x);
    x += dpp_rot<0x122>(x);
    x += dpp_rot<0x124>(x);
    x += dpp_rot<0x128>(x);
    return x;
}

// ---------------------------------------------------------------------------
// Kernel 0: split + transpose weights -> WT_hi (RNE) / WT_lo [H][C] bf16.
// ---------------------------------------------------------------------------
__global__ __launch_bounds__(256) void prep_w(
    const float* __restrict__ Wk, const float* __restrict__ Wq,
    const float* __restrict__ Wv, unsigned short* __restrict__ ws)
{
    const int h = blockIdx.x;
    const int mat = blockIdx.y;
    const float* W = (mat == 0) ? Wq : (mat == 1) ? Wk : Wv;
    unsigned short* hi = ws + 5 * kMH + (size_t)(mat * 2) * kWH;
    unsigned short* lo = hi + kWH;

    const int k0 = threadIdx.x * 4;
    unsigned short hv[4], lv[4];
#pragma unroll
    for (int j = 0; j < 4; ++j) {
        const float f = W[(size_t)(k0 + j) * kH + h];
        hv[j] = f2bf_rne(f);
        lv[j] = f2bf_rne(f - bf2f(hv[j]));
    }
    *(uint2*)&hi[(size_t)h * kC + k0] =
        make_uint2(((unsigned)hv[1] << 16) | hv[0], ((unsigned)hv[3] << 16) | hv[2]);
    *(uint2*)&lo[(size_t)h * kC + k0] =
        make_uint2(((unsigned)lv[1] << 16) | lv[0], ((unsigned)lv[3] << 16) | lv[2]);
}

// ---------------------------------------------------------------------------
// Kernel 1: QKV projection, A-in-register design.  (round-2 version, incl.
// row-major epilogue layouts -- the frag-order experiment was reverted.)
// ---------------------------------------------------------------------------
__global__ __launch_bounds__(256) void qkv_mfma(
    const float* __restrict__ x, unsigned short* __restrict__ ws)
{
    __shared__ __align__(16) unsigned short Bh[128 * 64];
    __shared__ __align__(16) unsigned short Bl[128 * 64];

    const int idx = blockIdx.x;
    const int mat = idx >> 8;               // 0=q, 1=k, 2=v
    const int m0 = (idx & 255) * 64;
    const unsigned short* wThi = ws + 5 * kMH + (size_t)(mat * 2) * kWH;
    const unsigned short* wTlo = wThi + kWH;

    const int tid = threadIdx.x;
    const int w = tid >> 6, lane = tid & 63;
    const int li = lane & 15, quad = lane >> 4;

    const float* xrow = x + (size_t)(m0 + w * 16 + li) * kC;

    f32x4 acc[8];
#pragma unroll
    for (int j = 0; j < 8; ++j) acc[j] = (f32x4){0.f, 0.f, 0.f, 0.f};

    for (int kt = 0; kt < kC; kt += 64) {
        if (kt) __syncthreads();
        // ---- stage B [128 rows][64 cols] hi(+lo) via swizzled DMA ----
#pragma unroll
        for (int u = 0; u < 4; ++u) {
            const int f = u * 256 + tid;
            const int row = f >> 3, g = (f & 7) ^ (row & 7);
            load_lds16(wThi + (size_t)row * kC + kt + g * 8, Bh + f * 8);
            if (mat <= 1)
                load_lds16(wTlo + (size_t)row * kC + kt + g * 8, Bl + f * 8);
        }
        // ---- A-frags in-register from global x ----
        float4 xa[2][2];
#pragma unroll
        for (int kc = 0; kc < 2; ++kc) {
            xa[kc][0] = *(const float4*)(xrow + kt + kc * 32 + quad * 8);
            xa[kc][1] = *(const float4*)(xrow + kt + kc * 32 + quad * 8 + 4);
        }
        bf16x8 ah[2], al[2];
        if (mat <= 1) {
#pragma unroll
            for (int kc = 0; kc < 2; ++kc) {
                const float4 a0 = xa[kc][0], a1 = xa[kc][1];
                unsigned int hp[4], lp[4];
                hp[0] = pack_hi2(a0.x, a0.y); hp[1] = pack_hi2(a0.z, a0.w);
                hp[2] = pack_hi2(a1.x, a1.y); hp[3] = pack_hi2(a1.z, a1.w);
                lp[0] = pack_hi2(a0.x - hi_part(a0.x), a0.y - hi_part(a0.y));
                lp[1] = pack_hi2(a0.z - hi_part(a0.z), a0.w - hi_part(a0.w));
                lp[2] = pack_hi2(a1.x - hi_part(a1.x), a1.y - hi_part(a1.y));
                lp[3] = pack_hi2(a1.z - hi_part(a1.z), a1.w - hi_part(a1.w));
                ah[kc] = *(bf16x8*)hp;
                al[kc] = *(bf16x8*)lp;
            }
        } else {
#pragma unroll
            for (int kc = 0; kc < 2; ++kc) {
                const float4 a0 = xa[kc][0], a1 = xa[kc][1];
                unsigned short e[8];
                e[0] = f2bf_rne(a0.x); e[1] = f2bf_rne(a0.y);
                e[2] = f2bf_rne(a0.z); e[3] = f2bf_rne(a0.w);
                e[4] = f2bf_rne(a1.x); e[5] = f2bf_rne(a1.y);
                e[6] = f2bf_rne(a1.z); e[7] = f2bf_rne(a1.w);
                ah[kc] = *(bf16x8*)e;
            }
        }
        __syncthreads();

        // ---- MFMA over all 128 cols ----
        if (mat <= 1) {
#pragma unroll
            for (int kc = 0; kc < 2; ++kc)
#pragma unroll
                for (int nt = 0; nt < 8; ++nt) {
                    const int row = nt * 16 + li;
                    const int pos = (kc * 4 + quad) ^ (row & 7);
                    const bf16x8 bh = *(const bf16x8*)&Bh[row * 64 + pos * 8];
                    const bf16x8 bl = *(const bf16x8*)&Bl[row * 64 + pos * 8];
                    acc[nt] = __builtin_amdgcn_mfma_f32_16x16x32_bf16(ah[kc], bh, acc[nt], 0, 0, 0);
                    acc[nt] = __builtin_amdgcn_mfma_f32_16x16x32_bf16(al[kc], bh, acc[nt], 0, 0, 0);
                    acc[nt] = __builtin_amdgcn_mfma_f32_16x16x32_bf16(ah[kc], bl, acc[nt], 0, 0, 0);
                }
        } else {
#pragma unroll
            for (int kc = 0; kc < 2; ++kc)
#pragma unroll
                for (int nt = 0; nt < 8; ++nt) {
                    const int row = nt * 16 + li;
                    const int pos = (kc * 4 + quad) ^ (row & 7);
                    const bf16x8 bh = *(const bf16x8*)&Bh[row * 64 + pos * 8];
                    acc[nt] = __builtin_amdgcn_mfma_f32_16x16x32_bf16(ah[kc], bh, acc[nt], 0, 0, 0);
                }
        }
    }

    // ---- epilogue ----
    if (mat <= 1) {
        unsigned short* hip_ = ws + (size_t)(mat * 2) * kMH;
        unsigned short* lop  = hip_ + kMH;
        const float sc = (mat == 0) ? QSCALE : 1.0f;
#pragma unroll
        for (int nt = 0; nt < 8; ++nt) {
            const int col = nt * 16 + li;
#pragma unroll
            for (int reg = 0; reg < 4; ++reg) {
                const int row = m0 + w * 16 + quad * 4 + reg;
                const float v = acc[nt][reg] * sc;
                hip_[(size_t)row * kH + col] = (unsigned short)(__float_as_uint(v) >> 16);
                lop[(size_t)row * kH + col] =
                    (unsigned short)(__float_as_uint(v - hi_part(v)) >> 16);
            }
        }
    } else {
        unsigned short* vt = ws + 4 * kMH;
        const int bb = m0 >> 11;
        const int t0 = (m0 & (kT - 1)) + w * 16 + quad * 4;
#pragma unroll
        for (int nt = 0; nt < 8; ++nt) {
            const int h = nt * 16 + li;
            ushort4 pk;
            pk.x = f2bf_rne(acc[nt][0]);
            pk.y = f2bf_rne(acc[nt][1]);
            pk.z = f2bf_rne(acc[nt][2]);
            pk.w = f2bf_rne(acc[nt][3]);
            *(ushort4*)&vt[((size_t)(bb * kH + h)) * kT + t0] = pk;
        }
    }
}

// ---------------------------------------------------------------------------
// Kernel 2: flash attention, barrier-free hot loop (round-2 structure:
// 32-row Q tiles, 512 blocks, qt/63-qt pairing, DPP softmax, row-major
// K/V loads).  Round-4 changes (latency ILP, no structural change):
//  (1) V register double-buffer: next chunk's 8 V loads are issued before
//      the current chunk's QK/softmax/PV, hiding ~400cy of L2 latency.
//      Named vfA/vfB buffers, all indices compile-time (no scratch).
//  (2) QK accumulators split into two chains (kc 0-1 -> s, kc 2-3 -> s2,
//      summed once): 8 independent 6-deep MFMA chains instead of 4x12-deep.
// ---------------------------------------------------------------------------
__global__ __launch_bounds__(256, 2) void attn_mfma(
    const unsigned short* __restrict__ ws, float* __restrict__ out)
{
    __shared__ __align__(16) unsigned short Ps[4][2][16][40];
    __shared__ __align__(16) float Ml[4][32][2];
    __shared__ __align__(16) float Obuf[3][32][128];

    const int tid = threadIdx.x;
    const int w = tid >> 6, lane = tid & 63;
    const int li = lane & 15, quad = lane >> 4;

    const int idx = blockIdx.x;
    const int b = idx & 7;
    const int j = idx >> 3;
    const int qt = (j < 32) ? j : 95 - j;   // pair qt with 63-qt per CU
    const int i0 = qt * 32;
    const int nc = qt + 1;                  // 32-col causal chunks

    const unsigned short* qhi = ws;
    const unsigned short* qlo = ws + kMH;
    const unsigned short* khi = ws + 2 * kMH;
    const unsigned short* klo = ws + 3 * kMH;
    const unsigned short* vt  = ws + 4 * kMH;

    // Q frags (A-layout), 2 m-tiles
    bf16x8 qh[2][4], ql[2][4];
#pragma unroll
    for (int mi = 0; mi < 2; ++mi) {
        const size_t qoff = ((size_t)(b * kT + i0 + mi * 16 + li)) * kH;
#pragma unroll
        for (int kc = 0; kc < 4; ++kc) {
            qh[mi][kc] = *(const bf16x8*)(qhi + qoff + kc * 32 + quad * 8);
            ql[mi][kc] = *(const bf16x8*)(qlo + qoff + kc * 32 + quad * 8);
        }
    }

    f32x4 o[2][8];
#pragma unroll
    for (int mi = 0; mi < 2; ++mi)
#pragma unroll
        for (int ht = 0; ht < 8; ++ht) o[mi][ht] = (f32x4){0.f, 0.f, 0.f, 0.f};
    float m_i[2][4], l_i[2][4];
#pragma unroll
    for (int mi = 0; mi < 2; ++mi)
#pragma unroll
        for (int reg = 0; reg < 4; ++reg) { m_i[mi][reg] = -3.0e38f; l_i[mi][reg] = 0.f; }

    // V loader (coalesced within 64B rows; quads cover consecutive 64B)
    auto loadV = [&](bf16x8 (&vf)[8], const int t0) {
#pragma unroll
        for (int ht = 0; ht < 8; ++ht)
            vf[ht] = *(const bf16x8*)(vt + (size_t)(b * kH + ht * 16 + li) * kT +
                                      t0 + quad * 8);
    };

    // one K-chunk: QK^T (split-bf16, split chains) -> mask -> online softmax
    // -> P via per-wave LDS -> PV.  vf must hold V for this chunk.
    auto computeChunk = [&](const bf16x8 (&vf)[8], const int jc) {
        const int t0 = jc * 32;
        f32x4 s[2][2], s2[2][2];
#pragma unroll
        for (int mi = 0; mi < 2; ++mi)
#pragma unroll
            for (int nt = 0; nt < 2; ++nt) {
                s[mi][nt] = (f32x4){0.f, 0.f, 0.f, 0.f};
                s2[mi][nt] = (f32x4){0.f, 0.f, 0.f, 0.f};
            }
#pragma unroll
        for (int kc = 0; kc < 4; ++kc) {
            bf16x8 kh[2], kl[2];
#pragma unroll
            for (int nt = 0; nt < 2; ++nt) {
                const size_t ka =
                    ((size_t)(b * kT + t0 + nt * 16 + li)) * kH + kc * 32 + quad * 8;
                kh[nt] = *(const bf16x8*)(khi + ka);
                kl[nt] = *(const bf16x8*)(klo + ka);
            }
            if (kc < 2) {
#pragma unroll
                for (int mi = 0; mi < 2; ++mi)
#pragma unroll
                    for (int nt = 0; nt < 2; ++nt) {
                        s[mi][nt] = __builtin_amdgcn_mfma_f32_16x16x32_bf16(qh[mi][kc], kh[nt], s[mi][nt], 0, 0, 0);
                        s[mi][nt] = __builtin_amdgcn_mfma_f32_16x16x32_bf16(ql[mi][kc], kh[nt], s[mi][nt], 0, 0, 0);
                        s[mi][nt] = __builtin_amdgcn_mfma_f32_16x16x32_bf16(qh[mi][kc], kl[nt], s[mi][nt], 0, 0, 0);
                    }
            } else {
#pragma unroll
                for (int mi = 0; mi < 2; ++mi)
#pragma unroll
                    for (int nt = 0; nt < 2; ++nt) {
                        s2[mi][nt] = __builtin_amdgcn_mfma_f32_16x16x32_bf16(qh[mi][kc], kh[nt], s2[mi][nt], 0, 0, 0);
                        s2[mi][nt] = __builtin_amdgcn_mfma_f32_16x16x32_bf16(ql[mi][kc], kh[nt], s2[mi][nt], 0, 0, 0);
                        s2[mi][nt] = __builtin_amdgcn_mfma_f32_16x16x32_bf16(qh[mi][kc], kl[nt], s2[mi][nt], 0, 0, 0);
                    }
            }
        }
#pragma unroll
        for (int mi = 0; mi < 2; ++mi)
#pragma unroll
            for (int nt = 0; nt < 2; ++nt) s[mi][nt] += s2[mi][nt];

        // causal mask (diagonal chunk only)
        if (jc == qt) {
#pragma unroll
            for (int mi = 0; mi < 2; ++mi) {
                const int grow0 = i0 + mi * 16 + quad * 4;
#pragma unroll
                for (int nt = 0; nt < 2; ++nt) {
                    const int gcol = t0 + nt * 16 + li;
#pragma unroll
                    for (int reg = 0; reg < 4; ++reg)
                        if (gcol > grow0 + reg) s[mi][nt][reg] = -3.0e38f;
                }
            }
        }
        // online softmax (exp2 domain), DPP row reduces
#pragma unroll
        for (int mi = 0; mi < 2; ++mi) {
            float alpha[4];
#pragma unroll
            for (int reg = 0; reg < 4; ++reg) {
                const float mr = rowmax16(fmaxf(s[mi][0][reg], s[mi][1][reg]));
                const float mn = fmaxf(m_i[mi][reg], mr);
                alpha[reg] = exp2f(m_i[mi][reg] - mn);
                m_i[mi][reg] = mn;
                const float p0 = exp2f(s[mi][0][reg] - mn);
                const float p1 = exp2f(s[mi][1][reg] - mn);
                s[mi][0][reg] = p0; s[mi][1][reg] = p1;
                const float rs = rowsum16(p0 + p1);
                l_i[mi][reg] = l_i[mi][reg] * alpha[reg] + rs;
            }
            const f32x4 av = {alpha[0], alpha[1], alpha[2], alpha[3]};
#pragma unroll
            for (int ht = 0; ht < 8; ++ht) o[mi][ht] *= av;
            // P -> per-wave LDS (C-layout) -> A-frag (same-wave, no barrier)
#pragma unroll
            for (int nt = 0; nt < 2; ++nt)
#pragma unroll
                for (int reg = 0; reg < 4; ++reg)
                    Ps[w][mi][quad * 4 + reg][nt * 16 + li] = f2bf_rne(s[mi][nt][reg]);
        }
#pragma unroll
        for (int mi = 0; mi < 2; ++mi) {
            const bf16x8 pf = *(const bf16x8*)&Ps[w][mi][li][quad * 8];
#pragma unroll
            for (int ht = 0; ht < 8; ++ht)
                o[mi][ht] = __builtin_amdgcn_mfma_f32_16x16x32_bf16(pf, vf[ht], o[mi][ht], 0, 0, 0);
        }
    };

    // ---- software-pipelined chunk loop (depth-1 V prefetch, A/B rotate) ----
    {
        bf16x8 vfA[8], vfB[8];
        int jc = w;
        if (jc < nc) loadV(vfA, jc * 32);
        while (jc < nc) {
            int jn = jc + 4;
            if (jn < nc) loadV(vfB, jn * 32);
            computeChunk(vfA, jc);
            jc = jn;
            if (jc >= nc) break;
            jn = jc + 4;
            if (jn < nc) loadV(vfA, jn * 32);
            computeChunk(vfB, jc);
            jc = jn;
        }
    }

    // ---- 4-way merge across waves ----
    if (li == 0) {
#pragma unroll
        for (int mi = 0; mi < 2; ++mi)
#pragma unroll
            for (int reg = 0; reg < 4; ++reg) {
                Ml[w][mi * 16 + quad * 4 + reg][0] = m_i[mi][reg];
                Ml[w][mi * 16 + quad * 4 + reg][1] = l_i[mi][reg];
            }
    }
    __syncthreads();
    float a_self[2][4], linv[2][4];
#pragma unroll
    for (int mi = 0; mi < 2; ++mi)
#pragma unroll
        for (int reg = 0; reg < 4; ++reg) {
            const int row = mi * 16 + quad * 4 + reg;
            const float m0_ = Ml[0][row][0], m1 = Ml[1][row][0];
            const float m2 = Ml[2][row][0], m3 = Ml[3][row][0];
            const float ms = fmaxf(fmaxf(m0_, m1), fmaxf(m2, m3));
            const float L = Ml[0][row][1] * exp2f(m0_ - ms) +
                            Ml[1][row][1] * exp2f(m1 - ms) +
                            Ml[2][row][1] * exp2f(m2 - ms) +
                            Ml[3][row][1] * exp2f(m3 - ms);
            a_self[mi][reg] = exp2f(m_i[mi][reg] - ms);
            linv[mi][reg] = 1.0f / L;
        }
    if (w) {
#pragma unroll
        for (int mi = 0; mi < 2; ++mi)
#pragma unroll
            for (int ht = 0; ht < 8; ++ht)
#pragma unroll
                for (int reg = 0; reg < 4; ++reg)
                    Obuf[w - 1][mi * 16 + quad * 4 + reg][ht * 16 + li] =
                        o[mi][ht][reg] * a_self[mi][reg];
    }
    __syncthreads();
    if (w == 0) {
#pragma unroll
        for (int mi = 0; mi < 2; ++mi)
#pragma unroll
            for (int ht = 0; ht < 8; ++ht)
#pragma unroll
                for (int reg = 0; reg < 4; ++reg) {
                    const int row = mi * 16 + quad * 4 + reg;
                    const int col = ht * 16 + li;
                    const float v = o[mi][ht][reg] * a_self[mi][reg] +
                                    Obuf[0][row][col] + Obuf[1][row][col] +
                                    Obuf[2][row][col];
                    out[(size_t)(b * kT + i0 + row) * kH + col] = v * linv[mi][reg];
                }
    }
}

// ---------------------------------------------------------------------------
extern "C" void kernel_launch(void* const* d_in, const int* in_sizes, int n_in,
                              void* d_out, int out_size, void* d_ws, size_t ws_size,
                              hipStream_t stream) {
    // setup_inputs order: x, Wk, Wq, Wv
    const float* x  = (const float*)d_in[0];
    const float* Wk = (const float*)d_in[1];
    const float* Wq = (const float*)d_in[2];
    const float* Wv = (const float*)d_in[3];
    unsigned short* ws = (unsigned short*)d_ws;
    float* out = (float*)d_out;

    hipLaunchKernelGGL(prep_w, dim3(128, 3), dim3(256), 0, stream, Wk, Wq, Wv, ws);
    hipLaunchKernelGGL(qkv_mfma, dim3(768), dim3(256), 0, stream, x, ws);
    hipLaunchKernelGGL(attn_mfma, dim3(512), dim3(256), 0, stream,
                       (const unsigned short*)ws, out);
}

// Round 5
// 187.743 us; speedup vs baseline: 1.4035x; 1.4035x over previous
//
#include <hip/hip_runtime.h>

// Problem constants: B=8, T=2048, C=1024, H=128
constexpr int kB = 8;
constexpr int kT = 2048;
constexpr int kC = 1024;
constexpr int kH = 128;
constexpr int kM = kB * kT;                 // 16384 rows
constexpr size_t kMH = (size_t)kM * kH;     // 2,097,152
constexpr size_t kWH = (size_t)kC * kH;     // 131,072

// q is pre-scaled by sqrt(C)*log2(e) so softmax can use exp2 directly.
#define QSCALE 46.166241308446828f          // 32 * 1.4426950408889634

typedef __attribute__((ext_vector_type(8))) short bf16x8;   // MFMA A/B frag
typedef __attribute__((ext_vector_type(4))) float f32x4;    // MFMA C/D frag

// ws layout (ushort): qhi | qlo | khi | klo | vT[B][H][T] | 6x WT (hi/lo per mat)

__device__ inline unsigned short f2bf_rne(float f) {
    union { float f; unsigned int u; } x; x.f = f;
    unsigned int r = x.u + 0x7fff + ((x.u >> 16) & 1);
    return (unsigned short)(r >> 16);
}
__device__ inline float bf2f(unsigned short h) {
    union { float f; unsigned int u; } x; x.u = ((unsigned int)h) << 16;
    return x.f;
}
__device__ inline unsigned int pack_hi2(float a, float b) {  // trunc-hi16 pack
    return __builtin_amdgcn_perm(__float_as_uint(b), __float_as_uint(a),
                                 0x07060302u);
}
__device__ inline float hi_part(float v) {
    return __uint_as_float(__float_as_uint(v) & 0xffff0000u);
}
__device__ inline void load_lds16(const unsigned short* g, unsigned short* l) {
    __builtin_amdgcn_global_load_lds(
        (const __attribute__((address_space(1))) unsigned int*)g,
        (__attribute__((address_space(3))) unsigned int*)l, 16, 0, 0);
}
// Raw v_exp_f32 (2^x). exp2f() may lower to the branchy __ocml wrapper;
// the hot loop issues 24 of these per chunk-iteration.
__device__ inline float fexp2(float x) { return __builtin_amdgcn_exp2f(x); }

// ---- DPP 16-lane row reductions (pure VALU: no ds_bpermute, no lgkmcnt) ----
template <int CTRL>
__device__ inline float dpp_rot(float x) {
    return __int_as_float(__builtin_amdgcn_update_dpp(
        0, __float_as_int(x), CTRL, 0xf, 0xf, false));
}
__device__ inline float rowmax16(float x) {
    x = fmaxf(x, dpp_rot<0x121>(x));   // ror:1
    x = fmaxf(x, dpp_rot<0x122>(x));   // ror:2
    x = fmaxf(x, dpp_rot<0x124>(x));   // ror:4
    x = fmaxf(x, dpp_rot<0x128>(x));   // ror:8
    return x;
}
__device__ inline float rowsum16(float x) {
    x += dpp_rot<0x121>(x);
    x += dpp_rot<0x122>(x);
    x += dpp_rot<0x124>(x);
    x += dpp_rot<0x128>(x);
    return x;
}

// ---------------------------------------------------------------------------
// Kernel 0: split + transpose weights -> WT_hi (RNE) / WT_lo [H][C] bf16.
// ---------------------------------------------------------------------------
__global__ __launch_bounds__(256) void prep_w(
    const float* __restrict__ Wk, const float* __restrict__ Wq,
    const float* __restrict__ Wv, unsigned short* __restrict__ ws)
{
    const int h = blockIdx.x;
    const int mat = blockIdx.y;
    const float* W = (mat == 0) ? Wq : (mat == 1) ? Wk : Wv;
    unsigned short* hi = ws + 5 * kMH + (size_t)(mat * 2) * kWH;
    unsigned short* lo = hi + kWH;

    const int k0 = threadIdx.x * 4;
    unsigned short hv[4], lv[4];
#pragma unroll
    for (int j = 0; j < 4; ++j) {
        const float f = W[(size_t)(k0 + j) * kH + h];
        hv[j] = f2bf_rne(f);
        lv[j] = f2bf_rne(f - bf2f(hv[j]));
    }
    *(uint2*)&hi[(size_t)h * kC + k0] =
        make_uint2(((unsigned)hv[1] << 16) | hv[0], ((unsigned)hv[3] << 16) | hv[2]);
    *(uint2*)&lo[(size_t)h * kC + k0] =
        make_uint2(((unsigned)lv[1] << 16) | lv[0], ((unsigned)lv[3] << 16) | lv[2]);
}

// ---------------------------------------------------------------------------
// Kernel 1: QKV projection, A-in-register design.  (round-2 version)
// ---------------------------------------------------------------------------
__global__ __launch_bounds__(256) void qkv_mfma(
    const float* __restrict__ x, unsigned short* __restrict__ ws)
{
    __shared__ __align__(16) unsigned short Bh[128 * 64];
    __shared__ __align__(16) unsigned short Bl[128 * 64];

    const int idx = blockIdx.x;
    const int mat = idx >> 8;               // 0=q, 1=k, 2=v
    const int m0 = (idx & 255) * 64;
    const unsigned short* wThi = ws + 5 * kMH + (size_t)(mat * 2) * kWH;
    const unsigned short* wTlo = wThi + kWH;

    const int tid = threadIdx.x;
    const int w = tid >> 6, lane = tid & 63;
    const int li = lane & 15, quad = lane >> 4;

    const float* xrow = x + (size_t)(m0 + w * 16 + li) * kC;

    f32x4 acc[8];
#pragma unroll
    for (int j = 0; j < 8; ++j) acc[j] = (f32x4){0.f, 0.f, 0.f, 0.f};

    for (int kt = 0; kt < kC; kt += 64) {
        if (kt) __syncthreads();
        // ---- stage B [128 rows][64 cols] hi(+lo) via swizzled DMA ----
#pragma unroll
        for (int u = 0; u < 4; ++u) {
            const int f = u * 256 + tid;
            const int row = f >> 3, g = (f & 7) ^ (row & 7);
            load_lds16(wThi + (size_t)row * kC + kt + g * 8, Bh + f * 8);
            if (mat <= 1)
                load_lds16(wTlo + (size_t)row * kC + kt + g * 8, Bl + f * 8);
        }
        // ---- A-frags in-register from global x ----
        float4 xa[2][2];
#pragma unroll
        for (int kc = 0; kc < 2; ++kc) {
            xa[kc][0] = *(const float4*)(xrow + kt + kc * 32 + quad * 8);
            xa[kc][1] = *(const float4*)(xrow + kt + kc * 32 + quad * 8 + 4);
        }
        bf16x8 ah[2], al[2];
        if (mat <= 1) {
#pragma unroll
            for (int kc = 0; kc < 2; ++kc) {
                const float4 a0 = xa[kc][0], a1 = xa[kc][1];
                unsigned int hp[4], lp[4];
                hp[0] = pack_hi2(a0.x, a0.y); hp[1] = pack_hi2(a0.z, a0.w);
                hp[2] = pack_hi2(a1.x, a1.y); hp[3] = pack_hi2(a1.z, a1.w);
                lp[0] = pack_hi2(a0.x - hi_part(a0.x), a0.y - hi_part(a0.y));
                lp[1] = pack_hi2(a0.z - hi_part(a0.z), a0.w - hi_part(a0.w));
                lp[2] = pack_hi2(a1.x - hi_part(a1.x), a1.y - hi_part(a1.y));
                lp[3] = pack_hi2(a1.z - hi_part(a1.z), a1.w - hi_part(a1.w));
                ah[kc] = *(bf16x8*)hp;
                al[kc] = *(bf16x8*)lp;
            }
        } else {
#pragma unroll
            for (int kc = 0; kc < 2; ++kc) {
                const float4 a0 = xa[kc][0], a1 = xa[kc][1];
                unsigned short e[8];
                e[0] = f2bf_rne(a0.x); e[1] = f2bf_rne(a0.y);
                e[2] = f2bf_rne(a0.z); e[3] = f2bf_rne(a0.w);
                e[4] = f2bf_rne(a1.x); e[5] = f2bf_rne(a1.y);
                e[6] = f2bf_rne(a1.z); e[7] = f2bf_rne(a1.w);
                ah[kc] = *(bf16x8*)e;
            }
        }
        __syncthreads();

        // ---- MFMA over all 128 cols ----
        if (mat <= 1) {
#pragma unroll
            for (int kc = 0; kc < 2; ++kc)
#pragma unroll
                for (int nt = 0; nt < 8; ++nt) {
                    const int row = nt * 16 + li;
                    const int pos = (kc * 4 + quad) ^ (row & 7);
                    const bf16x8 bh = *(const bf16x8*)&Bh[row * 64 + pos * 8];
                    const bf16x8 bl = *(const bf16x8*)&Bl[row * 64 + pos * 8];
                    acc[nt] = __builtin_amdgcn_mfma_f32_16x16x32_bf16(ah[kc], bh, acc[nt], 0, 0, 0);
                    acc[nt] = __builtin_amdgcn_mfma_f32_16x16x32_bf16(al[kc], bh, acc[nt], 0, 0, 0);
                    acc[nt] = __builtin_amdgcn_mfma_f32_16x16x32_bf16(ah[kc], bl, acc[nt], 0, 0, 0);
                }
        } else {
#pragma unroll
            for (int kc = 0; kc < 2; ++kc)
#pragma unroll
                for (int nt = 0; nt < 8; ++nt) {
                    const int row = nt * 16 + li;
                    const int pos = (kc * 4 + quad) ^ (row & 7);
                    const bf16x8 bh = *(const bf16x8*)&Bh[row * 64 + pos * 8];
                    acc[nt] = __builtin_amdgcn_mfma_f32_16x16x32_bf16(ah[kc], bh, acc[nt], 0, 0, 0);
                }
        }
    }

    // ---- epilogue ----
    if (mat <= 1) {
        unsigned short* hip_ = ws + (size_t)(mat * 2) * kMH;
        unsigned short* lop  = hip_ + kMH;
        const float sc = (mat == 0) ? QSCALE : 1.0f;
#pragma unroll
        for (int nt = 0; nt < 8; ++nt) {
            const int col = nt * 16 + li;
#pragma unroll
            for (int reg = 0; reg < 4; ++reg) {
                const int row = m0 + w * 16 + quad * 4 + reg;
                const float v = acc[nt][reg] * sc;
                hip_[(size_t)row * kH + col] = (unsigned short)(__float_as_uint(v) >> 16);
                lop[(size_t)row * kH + col] =
                    (unsigned short)(__float_as_uint(v - hi_part(v)) >> 16);
            }
        }
    } else {
        unsigned short* vt = ws + 4 * kMH;
        const int bb = m0 >> 11;
        const int t0 = (m0 & (kT - 1)) + w * 16 + quad * 4;
#pragma unroll
        for (int nt = 0; nt < 8; ++nt) {
            const int h = nt * 16 + li;
            ushort4 pk;
            pk.x = f2bf_rne(acc[nt][0]);
            pk.y = f2bf_rne(acc[nt][1]);
            pk.z = f2bf_rne(acc[nt][2]);
            pk.w = f2bf_rne(acc[nt][3]);
            *(ushort4*)&vt[((size_t)(bb * kH + h)) * kT + t0] = pk;
        }
    }
}

// ---------------------------------------------------------------------------
// Kernel 2: flash attention, barrier-free hot loop (round-2 structure:
// 32-row Q tiles, 512 blocks, qt/63-qt pairing, DPP softmax, row-major
// K/V loads).  Round-5 changes, both surgical on the R2 code:
//  (1) exp2f -> __builtin_amdgcn_exp2f (raw v_exp_f32; avoids the libm
//      wrapper -- 24 calls per chunk-iteration in the hot loop).
//  (2) K-frag depth-1 pipeline written INLINE (no lambdas, no array
//      references -- R4's lambda form spilled to scratch, WRITE_SIZE
//      8->203 MB).  kh/kl[2][2] rotate via cur/nxt = kc&1, all indices
//      compile-time after full unroll (same pattern compiled cleanly in R1).
// ---------------------------------------------------------------------------
__global__ __launch_bounds__(256, 2) void attn_mfma(
    const unsigned short* __restrict__ ws, float* __restrict__ out)
{
    __shared__ __align__(16) unsigned short Ps[4][2][16][40];
    __shared__ __align__(16) float Ml[4][32][2];
    __shared__ __align__(16) float Obuf[3][32][128];

    const int tid = threadIdx.x;
    const int w = tid >> 6, lane = tid & 63;
    const int li = lane & 15, quad = lane >> 4;

    const int idx = blockIdx.x;
    const int b = idx & 7;
    const int j = idx >> 3;
    const int qt = (j < 32) ? j : 95 - j;   // pair qt with 63-qt per CU
    const int i0 = qt * 32;
    const int nc = qt + 1;                  // 32-col causal chunks

    const unsigned short* qhi = ws;
    const unsigned short* qlo = ws + kMH;
    const unsigned short* khi = ws + 2 * kMH;
    const unsigned short* klo = ws + 3 * kMH;
    const unsigned short* vt  = ws + 4 * kMH;

    // Q frags (A-layout), 2 m-tiles
    bf16x8 qh[2][4], ql[2][4];
#pragma unroll
    for (int mi = 0; mi < 2; ++mi) {
        const size_t qoff = ((size_t)(b * kT + i0 + mi * 16 + li)) * kH;
#pragma unroll
        for (int kc = 0; kc < 4; ++kc) {
            qh[mi][kc] = *(const bf16x8*)(qhi + qoff + kc * 32 + quad * 8);
            ql[mi][kc] = *(const bf16x8*)(qlo + qoff + kc * 32 + quad * 8);
        }
    }

    f32x4 o[2][8];
#pragma unroll
    for (int mi = 0; mi < 2; ++mi)
#pragma unroll
        for (int ht = 0; ht < 8; ++ht) o[mi][ht] = (f32x4){0.f, 0.f, 0.f, 0.f};
    float m_i[2][4], l_i[2][4];
#pragma unroll
    for (int mi = 0; mi < 2; ++mi)
#pragma unroll
        for (int reg = 0; reg < 4; ++reg) { m_i[mi][reg] = -3.0e38f; l_i[mi][reg] = 0.f; }

    for (int jc = w; jc < nc; jc += 4) {
        const int t0 = jc * 32;
        // V B-frags (used at the end -> latency covered by QK+softmax)
        bf16x8 vf[8];
#pragma unroll
        for (int ht = 0; ht < 8; ++ht)
            vf[ht] = *(const bf16x8*)(vt + (size_t)(b * kH + ht * 16 + li) * kT +
                                      t0 + quad * 8);
        // S = Q K^T (split-bf16); K frags depth-1 pipelined over kc (inline,
        // constant indices after unroll)
        f32x4 s[2][2];
#pragma unroll
        for (int mi = 0; mi < 2; ++mi)
#pragma unroll
            for (int nt = 0; nt < 2; ++nt) s[mi][nt] = (f32x4){0.f, 0.f, 0.f, 0.f};
        bf16x8 kh[2][2], kl[2][2];
#pragma unroll
        for (int nt = 0; nt < 2; ++nt) {
            const size_t ka =
                ((size_t)(b * kT + t0 + nt * 16 + li)) * kH + quad * 8;
            kh[0][nt] = *(const bf16x8*)(khi + ka);
            kl[0][nt] = *(const bf16x8*)(klo + ka);
        }
#pragma unroll
        for (int kc = 0; kc < 4; ++kc) {
            const int cur = kc & 1, nxt = cur ^ 1;
            if (kc < 3) {
#pragma unroll
                for (int nt = 0; nt < 2; ++nt) {
                    const size_t ka = ((size_t)(b * kT + t0 + nt * 16 + li)) * kH +
                                      (kc + 1) * 32 + quad * 8;
                    kh[nxt][nt] = *(const bf16x8*)(khi + ka);
                    kl[nxt][nt] = *(const bf16x8*)(klo + ka);
                }
            }
#pragma unroll
            for (int mi = 0; mi < 2; ++mi)
#pragma unroll
                for (int nt = 0; nt < 2; ++nt) {
                    s[mi][nt] = __builtin_amdgcn_mfma_f32_16x16x32_bf16(qh[mi][kc], kh[cur][nt], s[mi][nt], 0, 0, 0);
                    s[mi][nt] = __builtin_amdgcn_mfma_f32_16x16x32_bf16(ql[mi][kc], kh[cur][nt], s[mi][nt], 0, 0, 0);
                    s[mi][nt] = __builtin_amdgcn_mfma_f32_16x16x32_bf16(qh[mi][kc], kl[cur][nt], s[mi][nt], 0, 0, 0);
                }
        }
        // causal mask (diagonal chunk only)
        if (jc == qt) {
#pragma unroll
            for (int mi = 0; mi < 2; ++mi) {
                const int grow0 = i0 + mi * 16 + quad * 4;
#pragma unroll
                for (int nt = 0; nt < 2; ++nt) {
                    const int gcol = t0 + nt * 16 + li;
#pragma unroll
                    for (int reg = 0; reg < 4; ++reg)
                        if (gcol > grow0 + reg) s[mi][nt][reg] = -3.0e38f;
                }
            }
        }
        // online softmax (exp2 domain), DPP row reduces, raw v_exp_f32
#pragma unroll
        for (int mi = 0; mi < 2; ++mi) {
            float alpha[4];
#pragma unroll
            for (int reg = 0; reg < 4; ++reg) {
                const float mr = rowmax16(fmaxf(s[mi][0][reg], s[mi][1][reg]));
                const float mn = fmaxf(m_i[mi][reg], mr);
                alpha[reg] = fexp2(m_i[mi][reg] - mn);
                m_i[mi][reg] = mn;
                const float p0 = fexp2(s[mi][0][reg] - mn);
                const float p1 = fexp2(s[mi][1][reg] - mn);
                s[mi][0][reg] = p0; s[mi][1][reg] = p1;
                const float rs = rowsum16(p0 + p1);
                l_i[mi][reg] = l_i[mi][reg] * alpha[reg] + rs;
            }
            const f32x4 av = {alpha[0], alpha[1], alpha[2], alpha[3]};
#pragma unroll
            for (int ht = 0; ht < 8; ++ht) o[mi][ht] *= av;
            // P -> per-wave LDS (C-layout) -> A-frag (same-wave, no barrier)
#pragma unroll
            for (int nt = 0; nt < 2; ++nt)
#pragma unroll
                for (int reg = 0; reg < 4; ++reg)
                    Ps[w][mi][quad * 4 + reg][nt * 16 + li] = f2bf_rne(s[mi][nt][reg]);
        }
#pragma unroll
        for (int mi = 0; mi < 2; ++mi) {
            const bf16x8 pf = *(const bf16x8*)&Ps[w][mi][li][quad * 8];
#pragma unroll
            for (int ht = 0; ht < 8; ++ht)
                o[mi][ht] = __builtin_amdgcn_mfma_f32_16x16x32_bf16(pf, vf[ht], o[mi][ht], 0, 0, 0);
        }
    }

    // ---- 4-way merge across waves ----
    if (li == 0) {
#pragma unroll
        for (int mi = 0; mi < 2; ++mi)
#pragma unroll
            for (int reg = 0; reg < 4; ++reg) {
                Ml[w][mi * 16 + quad * 4 + reg][0] = m_i[mi][reg];
                Ml[w][mi * 16 + quad * 4 + reg][1] = l_i[mi][reg];
            }
    }
    __syncthreads();
    float a_self[2][4], linv[2][4];
#pragma unroll
    for (int mi = 0; mi < 2; ++mi)
#pragma unroll
        for (int reg = 0; reg < 4; ++reg) {
            const int row = mi * 16 + quad * 4 + reg;
            const float m0_ = Ml[0][row][0], m1 = Ml[1][row][0];
            const float m2 = Ml[2][row][0], m3 = Ml[3][row][0];
            const float ms = fmaxf(fmaxf(m0_, m1), fmaxf(m2, m3));
            const float L = Ml[0][row][1] * fexp2(m0_ - ms) +
                            Ml[1][row][1] * fexp2(m1 - ms) +
                            Ml[2][row][1] * fexp2(m2 - ms) +
                            Ml[3][row][1] * fexp2(m3 - ms);
            a_self[mi][reg] = fexp2(m_i[mi][reg] - ms);
            linv[mi][reg] = 1.0f / L;
        }
    if (w) {
#pragma unroll
        for (int mi = 0; mi < 2; ++mi)
#pragma unroll
            for (int ht = 0; ht < 8; ++ht)
#pragma unroll
                for (int reg = 0; reg < 4; ++reg)
                    Obuf[w - 1][mi * 16 + quad * 4 + reg][ht * 16 + li] =
                        o[mi][ht][reg] * a_self[mi][reg];
    }
    __syncthreads();
    if (w == 0) {
#pragma unroll
        for (int mi = 0; mi < 2; ++mi)
#pragma unroll
            for (int ht = 0; ht < 8; ++ht)
#pragma unroll
                for (int reg = 0; reg < 4; ++reg) {
                    const int row = mi * 16 + quad * 4 + reg;
                    const int col = ht * 16 + li;
                    const float v = o[mi][ht][reg] * a_self[mi][reg] +
                                    Obuf[0][row][col] + Obuf[1][row][col] +
                                    Obuf[2][row][col];
                    out[(size_t)(b * kT + i0 + row) * kH + col] = v * linv[mi][reg];
                }
    }
}

// ---------------------------------------------------------------------------
extern "C" void kernel_launch(void* const* d_in, const int* in_sizes, int n_in,
                              void* d_out, int out_size, void* d_ws, size_t ws_size,
                              hipStream_t stream) {
    // setup_inputs order: x, Wk, Wq, Wv
    const float* x  = (const float*)d_in[0];
    const float* Wk = (const float*)d_in[1];
    const float* Wq = (const float*)d_in[2];
    const float* Wv = (const float*)d_in[3];
    unsigned short* ws = (unsigned short*)d_ws;
    float* out = (float*)d_out;

    hipLaunchKernelGGL(prep_w, dim3(128, 3), dim3(256), 0, stream, Wk, Wq, Wv, ws);
    hipLaunchKernelGGL(qkv_mfma, dim3(768), dim3(256), 0, stream, x, ws);
    hipLaunchKernelGGL(attn_mfma, dim3(512), dim3(256), 0, stream,
                       (const unsigned short*)ws, out);
}